// Round 1
// baseline (7097.123 us; speedup 1.0000x reference)
//
// 2-layer LSTM (B=256,T=512,IN=40,H=250) + linear head, persistent-kernel design.
// One cooperative kernel, 256 wgs x 256 thr (1 wg/CU). 8 batch-groups x 16
// unit-groups x 2 layers. W resident in LDS (bf16); B-frags preloaded in VGPRs.
// Flag-based producer/consumer sync per batch-group (no grid.sync).
// h broadcast via agent-scope atomic stores (LIC-direct; XCD-L2 safe).
#include <hip/hip_runtime.h>
#include <cstdint>

#define B_TOT 256
#define T_LEN 512
#define NX    40
#define NH    250
#define HP    256          // hidden padded (dummy units produce h=0, W cols 0)
#define XP    64           // x padded
#define K0    (XP + HP)    // 320  (layer0: [x | h1_prev])
#define K1    (HP + HP)    // 512  (layer1: [h1_t | h2_prev])
#define MB    32           // batches per wg
#define NU    16           // hidden units per wg
#define NR    64           // gate rows per wg (NU*4, r = lu*4 + gate, gate order i,f,g,o)
#define RING  8            // broadcast ring depth
#define LDSK  520          // LDS K-stride in ushorts (16B aligned, conflict-free b128)

typedef __attribute__((ext_vector_type(8))) short short8;
typedef __attribute__((ext_vector_type(4))) float float4v;
typedef __attribute__((ext_vector_type(4))) unsigned int uint4v;

__device__ __forceinline__ unsigned short f2bf(float f) {
  unsigned u = __float_as_uint(f);
  u += 0x7FFFu + ((u >> 16) & 1u);          // RNE
  return (unsigned short)(u >> 16);
}
__device__ __forceinline__ float bf2f(unsigned short h) {
  return __uint_as_float(((unsigned)h) << 16);
}
__device__ __forceinline__ float sigm(float x) { return 1.0f / (1.0f + __expf(-x)); }
__device__ __forceinline__ float tanh_f(float x) {
  float e = __expf(-2.0f * fabsf(x));
  float t = (1.0f - e) / (1.0f + e);
  return copysignf(t, x);
}
__device__ __forceinline__ void wait_ge(int* p, int v) {
  while (__hip_atomic_load(p, __ATOMIC_ACQUIRE, __HIP_MEMORY_SCOPE_AGENT) < v) {}
}

// ---------------------------------------------------------------------------
// Per-layer persistent loop. LAYER=0: x(40->64 pad)+h1_prev, K=320.
// LAYER=1: h1_t + h2_prev, K=512; gg==0 wgs also emit y[b, t-1].
// ---------------------------------------------------------------------------
template <int KSTEPS, int LAYER>
__device__ __forceinline__ void run_layer(
    int tid, int gb, int gg, int b0, int u0,
    const float* __restrict__ x, float* __restrict__ out, float blinv,
    unsigned short* __restrict__ h1bc, unsigned short* __restrict__ h2bc,
    int* c0p, int* c1p,
    unsigned short (*WL)[LDSK], unsigned short (*inA)[LDSK],
    float (*gbuf)[NR + 4], float* biasS, float* wlinS) {
  const int lane = tid & 63, wv = tid >> 6;
  const int quad = lane >> 4, l15 = lane & 15;
  const int Mt = wv & 1, Np = wv >> 1;   // wave -> (M-tile, N-tile-pair)

  // Preload B fragments (constant across time): B[k][n]=WL[n-row][k];
  // lane layout n = lane&15, k = quad*8 + j.
  short8 bfrag[2][KSTEPS];
#pragma unroll
  for (int ks = 0; ks < KSTEPS; ++ks) {
#pragma unroll
    for (int i = 0; i < 2; ++i)
      bfrag[i][ks] = *(const short8*)&WL[Np * 32 + i * 16 + l15][ks * 32 + quad * 8];
  }

  // cell state for (batch b0+tid>>3, units u0+2*(tid&7), +1): fp32 registers
  float cA = 0.f, cB = 0.f;
  int* myc = LAYER ? c1p : c0p;

  auto stage = [&](const unsigned short* __restrict__ src, int kofs) {
    int b = tid >> 3, c = tid & 7;   // 32 rows x 8 chunks of 64B
    const uint4v* s = (const uint4v*)(src + (size_t)b * HP + (size_t)c * 32);
    uint4v v0 = s[0], v1 = s[1], v2 = s[2], v3 = s[3];
    uint4v* d = (uint4v*)&inA[b][kofs + c * 32];
    d[0] = v0; d[1] = v1; d[2] = v2; d[3] = v3;
  };

#pragma unroll 1
  for (int t = 0; t < T_LEN; ++t) {
    // ---- wait for producers (thread0 polls, acquire) ----
    if (tid == 0) {
      if (LAYER == 0) {
        if (t > 0) wait_ge(c0p, 16 * t);                       // peers' h1[t-1]
        if (t >= RING) wait_ge(c1p, 16 * (t - RING + 1));      // ring back-pressure
      } else {
        wait_ge(c0p, 16 * (t + 1));                            // h1[t] ready
        if (t > 0) wait_ge(c1p, 16 * t);                       // peers' h2[t-1]
      }
    }
    __syncthreads();

    // ---- stage inputs into LDS (bf16) ----
    if (LAYER == 0) {
      if (tid < 128) {   // x[b, t, 0:40] -> inA[b][0:40] (40..63 stay zero)
        int b = tid >> 2, c = tid & 3;
        const float* xp = x + ((size_t)(b0 + b) * T_LEN + (size_t)t) * NX + c * 10;
#pragma unroll
        for (int j = 0; j < 10; ++j) inA[b][c * 10 + j] = f2bf(xp[j]);
      }
      if (t > 0)
        stage(h1bc + (size_t)((t - 1) & (RING - 1)) * B_TOT * HP + (size_t)b0 * HP, XP);
    } else {
      stage(h1bc + (size_t)(t & (RING - 1)) * B_TOT * HP + (size_t)b0 * HP, 0);
      if (t > 0)
        stage(h2bc + (size_t)((t - 1) & (RING - 1)) * B_TOT * HP + (size_t)b0 * HP, HP);
    }
    __syncthreads();

    // ---- gate GEMM: D[b][r] = sum_k inA[b][k] * WL[r][k] ----
    float4v acc0 = {0.f, 0.f, 0.f, 0.f};
    float4v acc1 = {0.f, 0.f, 0.f, 0.f};
#pragma unroll
    for (int ks = 0; ks < KSTEPS; ++ks) {
      short8 a = *(const short8*)&inA[Mt * 16 + l15][ks * 32 + quad * 8];
      acc0 = __builtin_amdgcn_mfma_f32_16x16x32_bf16(a, bfrag[0][ks], acc0, 0, 0, 0);
      acc1 = __builtin_amdgcn_mfma_f32_16x16x32_bf16(a, bfrag[1][ks], acc1, 0, 0, 0);
    }
    // dump C (row b = Mt*16+quad*4+reg, col r = Ntile*16 + l15)
#pragma unroll
    for (int reg = 0; reg < 4; ++reg) {
      gbuf[Mt * 16 + quad * 4 + reg][Np * 32 + l15] = acc0[reg];
      gbuf[Mt * 16 + quad * 4 + reg][Np * 32 + 16 + l15] = acc1[reg];
    }
    __syncthreads();

    // ---- gates + state update; write h (bf16, agent-scope atomic -> LIC) ----
    {
      int eb = tid >> 3, up = tid & 7;
      float4v ga = *(const float4v*)&gbuf[eb][up * 8];
      float4v gv = *(const float4v*)&gbuf[eb][up * 8 + 4];
      float iA = sigm(ga[0] + biasS[up * 8 + 0]);
      float fA = sigm(ga[1] + biasS[up * 8 + 1]);
      float gA = tanh_f(ga[2] + biasS[up * 8 + 2]);
      float oA = sigm(ga[3] + biasS[up * 8 + 3]);
      cA = fA * cA + iA * gA;
      float hA = oA * tanh_f(cA);
      float iB = sigm(gv[0] + biasS[up * 8 + 4]);
      float fB = sigm(gv[1] + biasS[up * 8 + 5]);
      float gB = tanh_f(gv[2] + biasS[up * 8 + 6]);
      float oB = sigm(gv[3] + biasS[up * 8 + 7]);
      cB = fB * cB + iB * gB;
      float hB = oB * tanh_f(cB);
      unsigned hv = (unsigned)f2bf(hA) | ((unsigned)f2bf(hB) << 16);
      unsigned* dst = (unsigned*)(LAYER ? h2bc : h1bc);
      size_t di = ((size_t)(t & (RING - 1)) * B_TOT * HP + (size_t)(b0 + eb) * HP + u0) >> 1;
      __hip_atomic_store(dst + di + up, hv, __ATOMIC_RELAXED, __HIP_MEMORY_SCOPE_AGENT);
    }

    // ---- head: y[b, t-1] from staged h2[t-1] (LAYER1, gg==0) ----
    if (LAYER == 1 && gg == 0 && t > 0) {
      int eb = tid >> 3, uc = tid & 7;
      float sum = 0.f;
#pragma unroll
      for (int j = 0; j < 4; ++j) {
        short8 hvv = *(const short8*)&inA[eb][HP + uc * 32 + j * 8];
#pragma unroll
        for (int e = 0; e < 8; ++e)
          sum += bf2f((unsigned short)hvv[e]) * wlinS[uc * 32 + j * 8 + e];
      }
      sum += __shfl_xor(sum, 1);
      sum += __shfl_xor(sum, 2);
      sum += __shfl_xor(sum, 4);
      if ((tid & 7) == 0)
        out[(size_t)(b0 + eb) * T_LEN + (t - 1)] = sigm(sum + blinv);
    }

    __syncthreads();               // drain h stores (barrier waits vmcnt(0))
    if (tid == 0) {
      __threadfence();
      __hip_atomic_fetch_add(myc, 1, __ATOMIC_RELEASE, __HIP_MEMORY_SCOPE_AGENT);
    }
  }

  // ---- epilogue: y[:, 511] after all layer1 wgs finished t=511 ----
  if (LAYER == 1 && gg == 0) {
    if (tid == 0) wait_ge(c1p, 16 * T_LEN);
    __syncthreads();
    int eb = tid >> 3, uc = tid & 7;
    const unsigned short* src =
        h2bc + (size_t)(511 & (RING - 1)) * B_TOT * HP + (size_t)(b0 + eb) * HP + uc * 32;
    float sum = 0.f;
#pragma unroll
    for (int j = 0; j < 4; ++j) {
      short8 hvv = *(const short8*)(src + j * 8);
#pragma unroll
      for (int e = 0; e < 8; ++e)
        sum += bf2f((unsigned short)hvv[e]) * wlinS[uc * 32 + j * 8 + e];
    }
    sum += __shfl_xor(sum, 1);
    sum += __shfl_xor(sum, 2);
    sum += __shfl_xor(sum, 4);
    if ((tid & 7) == 0)
      out[(size_t)(b0 + eb) * T_LEN + 511] = sigm(sum + blinv);
  }
}

// ---------------------------------------------------------------------------
extern "C" __global__ void __launch_bounds__(256, 1) lstm_persist(
    const float* __restrict__ x,
    const float* __restrict__ Wih0, const float* __restrict__ Whh0,
    const float* __restrict__ bih0, const float* __restrict__ bhh0,
    const float* __restrict__ Wih1, const float* __restrict__ Whh1,
    const float* __restrict__ bih1, const float* __restrict__ bhh1,
    const float* __restrict__ Wlin, const float* __restrict__ blin,
    float* __restrict__ out,
    unsigned short* __restrict__ h1bc, unsigned short* __restrict__ h2bc,
    int* __restrict__ cnt) {
  __shared__ unsigned short WL[NR][LDSK];    // 66560 B  bf16 [r][k], r = lu*4+gate
  __shared__ unsigned short inA[MB][LDSK];   // 33280 B  bf16 [b][k]
  __shared__ float gbuf[MB][NR + 4];         //  8704 B  fp32 gate preacts
  __shared__ float biasS[NR];
  __shared__ float wlinS[HP];

  const int tid = threadIdx.x;
  const int wg = blockIdx.x;
  const int layer = wg >> 7;
  const int gb = (wg >> 4) & 7;
  const int gg = wg & 15;
  const int b0 = gb * MB, u0 = gg * NU;

  // ---- one-time LDS fills ----
  {
    const float* Wih = layer ? Wih1 : Wih0;
    const float* Whh = layer ? Whh1 : Whh0;
    const float* bi = layer ? bih1 : bih0;
    const float* bh = layer ? bhh1 : bhh0;
    const int K = layer ? K1 : K0;
    const int xw = layer ? NH : NX;     // real width of input-part
    const int xofs = layer ? HP : XP;   // where h-part starts
    int r = tid >> 2, c = tid & 3;
    int lu = r >> 2, g = r & 3, ug = u0 + lu;
    int row = g * NH + ug;
    int kq = K >> 2;
    for (int k = c * kq; k < (c + 1) * kq; ++k) {
      float v = 0.f;
      if (ug < NH) {
        if (k < xw) v = Wih[(size_t)row * xw + k];
        else if (k >= xofs && k < xofs + NH) v = Whh[(size_t)row * NH + (k - xofs)];
      }
      WL[r][k] = f2bf(v);
    }
    if (tid < NR) {
      int lu2 = tid >> 2, g2 = tid & 3, ug2 = u0 + lu2;
      biasS[tid] = (ug2 < NH) ? (bi[g2 * NH + ug2] + bh[g2 * NH + ug2]) : 0.f;
    }
    if (tid < HP) wlinS[tid] = (tid < NH) ? Wlin[tid] : 0.f;
    for (int i = tid; i < MB * LDSK; i += 256) ((unsigned short*)inA)[i] = 0;
  }
  __syncthreads();

  float blinv = blin[0];
  int* c0p = cnt + gb * 32;          // layer0 completions, batch-group gb
  int* c1p = cnt + (8 + gb) * 32;    // layer1 completions

  if (layer == 0)
    run_layer<K0 / 32, 0>(tid, gb, gg, b0, u0, x, out, blinv, h1bc, h2bc,
                          c0p, c1p, WL, inA, gbuf, biasS, wlinS);
  else
    run_layer<K1 / 32, 1>(tid, gb, gg, b0, u0, x, out, blinv, h1bc, h2bc,
                          c0p, c1p, WL, inA, gbuf, biasS, wlinS);
}

extern "C" __global__ void prep_zero(int* cnt) {
  int i = threadIdx.x;
  if (i < 512) __hip_atomic_store(cnt + i, 0, __ATOMIC_RELAXED, __HIP_MEMORY_SCOPE_AGENT);
}

// ---------------------------------------------------------------------------
extern "C" void kernel_launch(void* const* d_in, const int* in_sizes, int n_in,
                              void* d_out, int out_size, void* d_ws, size_t ws_size,
                              hipStream_t stream) {
  const float* x    = (const float*)d_in[0];
  const float* Wih0 = (const float*)d_in[1];
  const float* Whh0 = (const float*)d_in[2];
  const float* bih0 = (const float*)d_in[3];
  const float* bhh0 = (const float*)d_in[4];
  const float* Wih1 = (const float*)d_in[5];
  const float* Whh1 = (const float*)d_in[6];
  const float* bih1 = (const float*)d_in[7];
  const float* bhh1 = (const float*)d_in[8];
  const float* Wlin = (const float*)d_in[9];
  const float* blin = (const float*)d_in[10];
  float* out = (float*)d_out;

  // workspace carve: h1bc 1MB | h2bc 1MB | counters 2KB
  unsigned short* h1bc = (unsigned short*)d_ws;
  unsigned short* h2bc = h1bc + (size_t)RING * B_TOT * HP;
  int* cnt = (int*)((char*)d_ws + 2u * (size_t)RING * B_TOT * HP * sizeof(unsigned short));

  hipLaunchKernelGGL(prep_zero, dim3(1), dim3(512), 0, stream, cnt);

  void* args[] = {&x, &Wih0, &Whh0, &bih0, &bhh0, &Wih1, &Whh1, &bih1, &bhh1,
                  &Wlin, &blin, &out, &h1bc, &h2bc, &cnt};
  hipLaunchCooperativeKernel((void*)lstm_persist, dim3(256), dim3(256), args, 0u, stream);
}

// Round 2
// 3327.039 us; speedup vs baseline: 2.1332x; 2.1332x over previous
//
// R2: 2-layer LSTM (B=256,T=512,IN=40,H=250) + linear head, persistent kernel.
// One cooperative kernel, 256 wgs x 256 thr (1 wg/CU). 8 batch-groups x 16
// unit-groups x 2 layers. W resident in LDS (bf16); B-frags preloaded in VGPRs.
// R2 change vs R1: sync protocol overhaul. R1 polled with agent-ACQUIRE loads
// (buffer_inv per iteration -> L2 thrash, 617 MB FETCH, 14 us/step). Now:
// per-wg slot counters, relaxed polling by wave0 lanes 0..31 (one slot each),
// ONE acquire fence per step, release-store signal (no threadfence, no RMW).
#include <hip/hip_runtime.h>
#include <cstdint>

#define B_TOT 256
#define T_LEN 512
#define NX    40
#define NH    250
#define HP    256          // hidden padded (dummy units produce h=0, W cols 0)
#define XP    64           // x padded
#define K0    (XP + HP)    // 320  (layer0: [x | h1_prev])
#define K1    (HP + HP)    // 512  (layer1: [h1_t | h2_prev])
#define MB    32           // batches per wg
#define NU    16           // hidden units per wg
#define NR    64           // gate rows per wg (NU*4, r = lu*4 + gate; i,f,g,o)
#define RING  8            // broadcast ring depth
#define LDSK  520          // LDS K-stride in ushorts (16B aligned)
#define SLOTS 16           // ints per slot (64B stride, own cache line)

typedef __attribute__((ext_vector_type(8))) short short8;
typedef __attribute__((ext_vector_type(4))) float float4v;
typedef __attribute__((ext_vector_type(4))) unsigned int uint4v;

__device__ __forceinline__ unsigned short f2bf(float f) {
  unsigned u = __float_as_uint(f);
  u += 0x7FFFu + ((u >> 16) & 1u);          // RNE
  return (unsigned short)(u >> 16);
}
__device__ __forceinline__ float bf2f(unsigned short h) {
  return __uint_as_float(((unsigned)h) << 16);
}
__device__ __forceinline__ float sigm(float x) { return 1.0f / (1.0f + __expf(-x)); }
__device__ __forceinline__ float tanh_f(float x) {
  float e = __expf(-2.0f * fabsf(x));
  float t = (1.0f - e) / (1.0f + e);
  return copysignf(t, x);
}

// ---------------------------------------------------------------------------
// Per-layer persistent loop. LAYER=0: x(40->64 pad)+h1_prev, K=320.
// LAYER=1: h1_t + h2_prev, K=512; gg==0 wgs also emit y[b, t-1] (after signal).
// Slot value = number of completed steps by that wg.
// ---------------------------------------------------------------------------
template <int KSTEPS, int LAYER>
__device__ __forceinline__ void run_layer(
    int tid, int gg, int b0, int u0,
    const float* __restrict__ x, float* __restrict__ out, float blinv,
    unsigned short* __restrict__ h1bc, unsigned short* __restrict__ h2bc,
    int* __restrict__ c0s, int* __restrict__ c1s, int* __restrict__ mys,
    unsigned short (*WL)[LDSK], unsigned short (*inA)[LDSK],
    float (*gbuf)[NR + 4], float* biasS, float* wlinS) {
  const int lane = tid & 63, wv = tid >> 6;
  const int quad = lane >> 4, l15 = lane & 15;
  const int Mt = wv & 1, Np = wv >> 1;   // wave -> (M-tile, N-tile-pair)

  // Preload B fragments (constant across time): B[k][n]=WL[n-row][k];
  // lane layout n = lane&15, k = quad*8 + j.
  short8 bfrag[2][KSTEPS];
#pragma unroll
  for (int ks = 0; ks < KSTEPS; ++ks) {
#pragma unroll
    for (int i = 0; i < 2; ++i)
      bfrag[i][ks] = *(const short8*)&WL[Np * 32 + i * 16 + l15][ks * 32 + quad * 8];
  }

  // cell state for (batch b0+tid>>3, units u0+2*(tid&7), +1): fp32 registers
  float cA = 0.f, cB = 0.f;

  auto stage = [&](const unsigned short* __restrict__ src, int kofs) {
    int b = tid >> 3, c = tid & 7;   // 32 rows x 8 chunks of 64B
    const uint4v* s = (const uint4v*)(src + (size_t)b * HP + (size_t)c * 32);
    uint4v v0 = s[0], v1 = s[1], v2 = s[2], v3 = s[3];
    uint4v* d = (uint4v*)&inA[b][kofs + c * 32];
    d[0] = v0; d[1] = v1; d[2] = v2; d[3] = v3;
  };

#pragma unroll 1
  for (int t = 0; t < T_LEN; ++t) {
    // ---- wait for producers: wave0 lanes 0..31 poll one slot each (relaxed)
    if (wv == 0) {
      if (lane < 32) {
        const int* sl = ((lane < 16) ? c0s : c1s) + (lane & 15) * SLOTS;
        int thr;
        if (LAYER == 0) thr = (lane < 16) ? t : (t - RING + 1);
        else            thr = (lane < 16) ? (t + 1) : t;
        while (__hip_atomic_load(sl, __ATOMIC_RELAXED, __HIP_MEMORY_SCOPE_AGENT) < thr) {
          __builtin_amdgcn_s_sleep(1);
        }
      }
      __builtin_amdgcn_fence(__ATOMIC_ACQUIRE, "agent");  // one inv per step
    }
    __syncthreads();

    // ---- stage inputs into LDS (bf16), plain b128 loads ----
    if (LAYER == 0) {
      if (tid < 128) {   // x[b, t, 0:40] -> inA[b][0:40] (40..63 stay zero)
        int b = tid >> 2, c = tid & 3;
        const float* xp = x + ((size_t)(b0 + b) * T_LEN + (size_t)t) * NX + c * 10;
#pragma unroll
        for (int j = 0; j < 10; ++j) inA[b][c * 10 + j] = f2bf(xp[j]);
      }
      if (t > 0)
        stage(h1bc + (size_t)((t - 1) & (RING - 1)) * B_TOT * HP + (size_t)b0 * HP, XP);
    } else {
      stage(h1bc + (size_t)(t & (RING - 1)) * B_TOT * HP + (size_t)b0 * HP, 0);
      if (t > 0)
        stage(h2bc + (size_t)((t - 1) & (RING - 1)) * B_TOT * HP + (size_t)b0 * HP, HP);
    }
    __syncthreads();

    // ---- gate GEMM: D[b][r] = sum_k inA[b][k] * WL[r][k] ----
    float4v acc0 = {0.f, 0.f, 0.f, 0.f};
    float4v acc1 = {0.f, 0.f, 0.f, 0.f};
#pragma unroll
    for (int ks = 0; ks < KSTEPS; ++ks) {
      short8 a = *(const short8*)&inA[Mt * 16 + l15][ks * 32 + quad * 8];
      acc0 = __builtin_amdgcn_mfma_f32_16x16x32_bf16(a, bfrag[0][ks], acc0, 0, 0, 0);
      acc1 = __builtin_amdgcn_mfma_f32_16x16x32_bf16(a, bfrag[1][ks], acc1, 0, 0, 0);
    }
    // dump C (row b = Mt*16+quad*4+reg, col r = Ntile*16 + l15)
#pragma unroll
    for (int reg = 0; reg < 4; ++reg) {
      gbuf[Mt * 16 + quad * 4 + reg][Np * 32 + l15] = acc0[reg];
      gbuf[Mt * 16 + quad * 4 + reg][Np * 32 + 16 + l15] = acc1[reg];
    }
    __syncthreads();

    // ---- gates + state update; write h (bf16, sc1 write-through to LIC) ----
    {
      int eb = tid >> 3, up = tid & 7;
      float4v ga = *(const float4v*)&gbuf[eb][up * 8];
      float4v gv = *(const float4v*)&gbuf[eb][up * 8 + 4];
      float iA = sigm(ga[0] + biasS[up * 8 + 0]);
      float fA = sigm(ga[1] + biasS[up * 8 + 1]);
      float gA = tanh_f(ga[2] + biasS[up * 8 + 2]);
      float oA = sigm(ga[3] + biasS[up * 8 + 3]);
      cA = fA * cA + iA * gA;
      float hA = oA * tanh_f(cA);
      float iB = sigm(gv[0] + biasS[up * 8 + 4]);
      float fB = sigm(gv[1] + biasS[up * 8 + 5]);
      float gB = tanh_f(gv[2] + biasS[up * 8 + 6]);
      float oB = sigm(gv[3] + biasS[up * 8 + 7]);
      cB = fB * cB + iB * gB;
      float hB = oB * tanh_f(cB);
      unsigned hv = (unsigned)f2bf(hA) | ((unsigned)f2bf(hB) << 16);
      unsigned* dst = (unsigned*)(LAYER ? h2bc : h1bc);
      size_t di = ((size_t)(t & (RING - 1)) * B_TOT * HP + (size_t)(b0 + eb) * HP + u0) >> 1;
      __hip_atomic_store(dst + di + up, hv, __ATOMIC_RELAXED, __HIP_MEMORY_SCOPE_AGENT);
    }

    // barrier waits each wave's vmcnt(0) -> h stores are LIC-visible; then signal
    __syncthreads();
    if (tid == 0)
      __hip_atomic_store(mys, t + 1, __ATOMIC_RELEASE, __HIP_MEMORY_SCOPE_AGENT);

    // ---- head: y[b, t-1] from staged h2[t-1] — AFTER signal (off crit path)
    if (LAYER == 1 && gg == 0 && t > 0) {
      int eb = tid >> 3, uc = tid & 7;
      float sum = 0.f;
#pragma unroll
      for (int j = 0; j < 4; ++j) {
        short8 hvv = *(const short8*)&inA[eb][HP + uc * 32 + j * 8];
#pragma unroll
        for (int e = 0; e < 8; ++e)
          sum += bf2f((unsigned short)hvv[e]) * wlinS[uc * 32 + j * 8 + e];
      }
      sum += __shfl_xor(sum, 1);
      sum += __shfl_xor(sum, 2);
      sum += __shfl_xor(sum, 4);
      if ((tid & 7) == 0)
        out[(size_t)(b0 + eb) * T_LEN + (t - 1)] = sigm(sum + blinv);
    }
  }

  // ---- epilogue: y[:, 511] after all layer1 wgs finished t=511 ----
  if (LAYER == 1 && gg == 0) {
    if (wv == 0) {
      if (lane < 16) {
        const int* sl = c1s + lane * SLOTS;
        while (__hip_atomic_load(sl, __ATOMIC_RELAXED, __HIP_MEMORY_SCOPE_AGENT) < T_LEN) {
          __builtin_amdgcn_s_sleep(1);
        }
      }
      __builtin_amdgcn_fence(__ATOMIC_ACQUIRE, "agent");
    }
    __syncthreads();
    int eb = tid >> 3, uc = tid & 7;
    const unsigned short* src =
        h2bc + (size_t)(511 & (RING - 1)) * B_TOT * HP + (size_t)(b0 + eb) * HP + uc * 32;
    float sum = 0.f;
#pragma unroll
    for (int j = 0; j < 4; ++j) {
      short8 hvv = *(const short8*)(src + j * 8);
#pragma unroll
      for (int e = 0; e < 8; ++e)
        sum += bf2f((unsigned short)hvv[e]) * wlinS[uc * 32 + j * 8 + e];
    }
    sum += __shfl_xor(sum, 1);
    sum += __shfl_xor(sum, 2);
    sum += __shfl_xor(sum, 4);
    if ((tid & 7) == 0)
      out[(size_t)(b0 + eb) * T_LEN + 511] = sigm(sum + blinv);
  }
}

// ---------------------------------------------------------------------------
extern "C" __global__ void __launch_bounds__(256, 1) lstm_persist(
    const float* __restrict__ x,
    const float* __restrict__ Wih0, const float* __restrict__ Whh0,
    const float* __restrict__ bih0, const float* __restrict__ bhh0,
    const float* __restrict__ Wih1, const float* __restrict__ Whh1,
    const float* __restrict__ bih1, const float* __restrict__ bhh1,
    const float* __restrict__ Wlin, const float* __restrict__ blin,
    float* __restrict__ out,
    unsigned short* __restrict__ h1bc, unsigned short* __restrict__ h2bc,
    int* __restrict__ cnt) {
  __shared__ unsigned short WL[NR][LDSK];    // 66560 B  bf16 [r][k], r = lu*4+gate
  __shared__ unsigned short inA[MB][LDSK];   // 33280 B  bf16 [b][k]
  __shared__ float gbuf[MB][NR + 4];         //  8704 B  fp32 gate preacts
  __shared__ float biasS[NR];
  __shared__ float wlinS[HP];

  const int tid = threadIdx.x;
  const int wg = blockIdx.x;
  const int layer = wg >> 7;
  const int gb = (wg >> 4) & 7;
  const int gg = wg & 15;
  const int b0 = gb * MB, u0 = gg * NU;

  // ---- one-time LDS fills ----
  {
    const float* Wih = layer ? Wih1 : Wih0;
    const float* Whh = layer ? Whh1 : Whh0;
    const float* bi = layer ? bih1 : bih0;
    const float* bh = layer ? bhh1 : bhh0;
    const int K = layer ? K1 : K0;
    const int xw = layer ? NH : NX;     // real width of input-part
    const int xofs = layer ? HP : XP;   // where h-part starts
    int r = tid >> 2, c = tid & 3;
    int lu = r >> 2, g = r & 3, ug = u0 + lu;
    int row = g * NH + ug;
    int kq = K >> 2;
    for (int k = c * kq; k < (c + 1) * kq; ++k) {
      float v = 0.f;
      if (ug < NH) {
        if (k < xw) v = Wih[(size_t)row * xw + k];
        else if (k >= xofs && k < xofs + NH) v = Whh[(size_t)row * NH + (k - xofs)];
      }
      WL[r][k] = f2bf(v);
    }
    if (tid < NR) {
      int lu2 = tid >> 2, g2 = tid & 3, ug2 = u0 + lu2;
      biasS[tid] = (ug2 < NH) ? (bi[g2 * NH + ug2] + bh[g2 * NH + ug2]) : 0.f;
    }
    if (tid < HP) wlinS[tid] = (tid < NH) ? Wlin[tid] : 0.f;
    for (int i = tid; i < MB * LDSK; i += 256) ((unsigned short*)inA)[i] = 0;
  }
  __syncthreads();

  float blinv = blin[0];
  int* c0s = cnt + gb * 16 * SLOTS;              // layer0 slots, batch-group gb
  int* c1s = cnt + (8 + gb) * 16 * SLOTS;        // layer1 slots
  int* mys = (layer ? c1s : c0s) + gg * SLOTS;   // own slot

  if (layer == 0)
    run_layer<K0 / 32, 0>(tid, gg, b0, u0, x, out, blinv, h1bc, h2bc,
                          c0s, c1s, mys, WL, inA, gbuf, biasS, wlinS);
  else
    run_layer<K1 / 32, 1>(tid, gg, b0, u0, x, out, blinv, h1bc, h2bc,
                          c0s, c1s, mys, WL, inA, gbuf, biasS, wlinS);
}

extern "C" __global__ void prep_zero(int* cnt) {
  int i = blockIdx.x * 256 + threadIdx.x;
  if (i < 2 * 8 * 16 * SLOTS)
    __hip_atomic_store(cnt + i, 0, __ATOMIC_RELAXED, __HIP_MEMORY_SCOPE_AGENT);
}

// ---------------------------------------------------------------------------
extern "C" void kernel_launch(void* const* d_in, const int* in_sizes, int n_in,
                              void* d_out, int out_size, void* d_ws, size_t ws_size,
                              hipStream_t stream) {
  const float* x    = (const float*)d_in[0];
  const float* Wih0 = (const float*)d_in[1];
  const float* Whh0 = (const float*)d_in[2];
  const float* bih0 = (const float*)d_in[3];
  const float* bhh0 = (const float*)d_in[4];
  const float* Wih1 = (const float*)d_in[5];
  const float* Whh1 = (const float*)d_in[6];
  const float* bih1 = (const float*)d_in[7];
  const float* bhh1 = (const float*)d_in[8];
  const float* Wlin = (const float*)d_in[9];
  const float* blin = (const float*)d_in[10];
  float* out = (float*)d_out;

  // workspace carve: h1bc 2MB | h2bc 2MB | slot counters 16KB
  unsigned short* h1bc = (unsigned short*)d_ws;
  unsigned short* h2bc = h1bc + (size_t)RING * B_TOT * HP;
  int* cnt = (int*)((char*)d_ws + 2u * (size_t)RING * B_TOT * HP * sizeof(unsigned short));

  hipLaunchKernelGGL(prep_zero, dim3(16), dim3(256), 0, stream, cnt);

  void* args[] = {&x, &Wih0, &Whh0, &bih0, &bhh0, &Wih1, &Whh1, &bih1, &bhh1,
                  &Wlin, &blin, &out, &h1bc, &h2bc, &cnt};
  hipLaunchCooperativeKernel((void*)lstm_persist, dim3(256), dim3(256), args, 0u, stream);
}

// Round 3
// 1478.093 us; speedup vs baseline: 4.8015x; 2.2509x over previous
//
// R3: 2-layer LSTM (B=256,T=512,IN=40,H=250) + linear head, persistent kernel.
// Topology (unchanged): 256 wgs x 256 thr (1 wg/CU), 8 batch-groups x 16
// unit-groups x 2 layers; W in LDS (bf16), B-frags in VGPRs; flag sync.
// R3 change vs R2: ZERO cache-maintenance ops in the steady-state loop.
//  - h staging loads are device-scope relaxed atomics (global_load_dword sc1,
//    read LIC directly) -> acquire fence (buffer_inv, L2-wide) deleted.
//  - signal is a relaxed sc1 store; ordering comes from __syncthreads' vmcnt(0)
//    drain of the sc1 write-through h stores -> release (wbl2) deleted.
//  R2 paid 256 wgs x (inv + wbl2) per step serializing at the TCCs and
//  re-fetching x forever (FETCH stuck at 658 MB, 6.5 us/step).
#include <hip/hip_runtime.h>
#include <cstdint>

#define B_TOT 256
#define T_LEN 512
#define NX    40
#define NH    250
#define HP    256          // hidden padded (dummy units produce h=0, W cols 0)
#define XP    64           // x padded
#define K0    (XP + HP)    // 320  (layer0: [x | h1_prev])
#define K1    (HP + HP)    // 512  (layer1: [h1_t | h2_prev])
#define MB    32           // batches per wg
#define NU    16           // hidden units per wg
#define NR    64           // gate rows per wg (NU*4, r = lu*4 + gate; i,f,g,o)
#define RING  8            // broadcast ring depth
#define LDSK  520          // LDS K-stride in ushorts (16B aligned; 260 dwords)
#define SLOTS 16           // ints per slot (64B stride, own cache line)

typedef __attribute__((ext_vector_type(8))) short short8;
typedef __attribute__((ext_vector_type(4))) float float4v;

__device__ __forceinline__ unsigned short f2bf(float f) {
  unsigned u = __float_as_uint(f);
  u += 0x7FFFu + ((u >> 16) & 1u);          // RNE
  return (unsigned short)(u >> 16);
}
__device__ __forceinline__ float bf2f(unsigned short h) {
  return __uint_as_float(((unsigned)h) << 16);
}
__device__ __forceinline__ float sigm(float x) { return 1.0f / (1.0f + __expf(-x)); }
__device__ __forceinline__ float tanh_f(float x) {
  float e = __expf(-2.0f * fabsf(x));
  float t = (1.0f - e) / (1.0f + e);
  return copysignf(t, x);
}
__device__ __forceinline__ unsigned ld_lic(const unsigned* p) {   // sc1 dword load
  return __hip_atomic_load(p, __ATOMIC_RELAXED, __HIP_MEMORY_SCOPE_AGENT);
}

// ---------------------------------------------------------------------------
// Per-layer persistent loop. LAYER=0: x(40->64 pad)+h1_prev, K=320.
// LAYER=1: h1_t + h2_prev, K=512; gg==0 wgs also emit y[b, t-1] (after signal).
// Slot value = number of completed steps by that wg.
// ---------------------------------------------------------------------------
template <int KSTEPS, int LAYER>
__device__ __forceinline__ void run_layer(
    int tid, int gg, int b0, int u0,
    const float* __restrict__ x, float* __restrict__ out, float blinv,
    unsigned short* __restrict__ h1bc, unsigned short* __restrict__ h2bc,
    int* __restrict__ c0s, int* __restrict__ c1s, int* __restrict__ mys,
    unsigned short (*WL)[LDSK], unsigned short (*inA)[LDSK],
    float (*gbuf)[NR + 4], float* biasS, float* wlinS) {
  const int lane = tid & 63, wv = tid >> 6;
  const int quad = lane >> 4, l15 = lane & 15;
  const int Mt = wv & 1, Np = wv >> 1;   // wave -> (M-tile, N-tile-pair)

  // Preload B fragments (constant across time): B[k][n]=WL[n-row][k];
  // lane layout n = lane&15, k = quad*8 + j.
  short8 bfrag[2][KSTEPS];
#pragma unroll
  for (int ks = 0; ks < KSTEPS; ++ks) {
#pragma unroll
    for (int i = 0; i < 2; ++i)
      bfrag[i][ks] = *(const short8*)&WL[Np * 32 + i * 16 + l15][ks * 32 + quad * 8];
  }

  // cell state for (batch b0+tid>>3, units u0+2*(tid&7), +1): fp32 registers
  float cA = 0.f, cB = 0.f;

#pragma unroll 1
  for (int t = 0; t < T_LEN; ++t) {
    // ---- wait for producers: wave0 lanes 0..31 poll one slot each (relaxed
    //      sc1 loads; NO fence — staging loads below read LIC themselves)
    if (wv == 0 && lane < 32) {
      const int* sl = ((lane < 16) ? c0s : c1s) + (lane & 15) * SLOTS;
      int thr;
      if (LAYER == 0) thr = (lane < 16) ? t : (t - RING + 1);
      else            thr = (lane < 16) ? (t + 1) : t;
      while (__hip_atomic_load(sl, __ATOMIC_RELAXED, __HIP_MEMORY_SCOPE_AGENT) < thr) {
        __builtin_amdgcn_s_sleep(1);
      }
    }
    __syncthreads();

    // ---- stage inputs into LDS (bf16). h via sc1 dword loads (LIC-fresh),
    //      coalesced: thread reads dwords tid + k*256 of the 16 KB block.
    if (LAYER == 0) {
      if (t > 0) {
        const unsigned* s1 =
            (const unsigned*)(h1bc + (size_t)((t - 1) & (RING - 1)) * B_TOT * HP +
                              (size_t)b0 * HP);
        unsigned v[16];
#pragma unroll
        for (int k = 0; k < 16; ++k) v[k] = ld_lic(s1 + tid + k * 256);
#pragma unroll
        for (int k = 0; k < 16; ++k) {
          int d = tid + k * 256;                 // row d>>7, dword col d&127
          ((unsigned*)&inA[d >> 7][0])[32 + (d & 127)] = v[k];   // +XP ushorts
        }
      }
      if (tid < 128) {   // x[b, t, 0:40] -> inA[b][0:40] (40..63 stay zero)
        int b = tid >> 2, c = tid & 3;
        const float* xp = x + ((size_t)(b0 + b) * T_LEN + (size_t)t) * NX + c * 10;
#pragma unroll
        for (int j = 0; j < 10; ++j) inA[b][c * 10 + j] = f2bf(xp[j]);
      }
    } else {
      const unsigned* s1 =
          (const unsigned*)(h1bc + (size_t)(t & (RING - 1)) * B_TOT * HP +
                            (size_t)b0 * HP);
      unsigned va[16], vb[16];
#pragma unroll
      for (int k = 0; k < 16; ++k) va[k] = ld_lic(s1 + tid + k * 256);
      if (t > 0) {
        const unsigned* s2 =
            (const unsigned*)(h2bc + (size_t)((t - 1) & (RING - 1)) * B_TOT * HP +
                              (size_t)b0 * HP);
#pragma unroll
        for (int k = 0; k < 16; ++k) vb[k] = ld_lic(s2 + tid + k * 256);
      }
#pragma unroll
      for (int k = 0; k < 16; ++k) {
        int d = tid + k * 256;
        unsigned* row = (unsigned*)&inA[d >> 7][0];
        row[d & 127] = va[k];                    // h1 at ushort 0
        if (t > 0) row[128 + (d & 127)] = vb[k]; // h2 at ushort HP
      }
    }
    __syncthreads();

    // ---- gate GEMM: D[b][r] = sum_k inA[b][k] * WL[r][k] ----
    float4v acc0 = {0.f, 0.f, 0.f, 0.f};
    float4v acc1 = {0.f, 0.f, 0.f, 0.f};
#pragma unroll
    for (int ks = 0; ks < KSTEPS; ++ks) {
      short8 a = *(const short8*)&inA[Mt * 16 + l15][ks * 32 + quad * 8];
      acc0 = __builtin_amdgcn_mfma_f32_16x16x32_bf16(a, bfrag[0][ks], acc0, 0, 0, 0);
      acc1 = __builtin_amdgcn_mfma_f32_16x16x32_bf16(a, bfrag[1][ks], acc1, 0, 0, 0);
    }
    // dump C (row b = Mt*16+quad*4+reg, col r = Ntile*16 + l15)
#pragma unroll
    for (int reg = 0; reg < 4; ++reg) {
      gbuf[Mt * 16 + quad * 4 + reg][Np * 32 + l15] = acc0[reg];
      gbuf[Mt * 16 + quad * 4 + reg][Np * 32 + 16 + l15] = acc1[reg];
    }
    __syncthreads();

    // ---- gates + state update; write h (bf16, sc1 write-through to LIC) ----
    {
      int eb = tid >> 3, up = tid & 7;
      float4v ga = *(const float4v*)&gbuf[eb][up * 8];
      float4v gv = *(const float4v*)&gbuf[eb][up * 8 + 4];
      float iA = sigm(ga[0] + biasS[up * 8 + 0]);
      float fA = sigm(ga[1] + biasS[up * 8 + 1]);
      float gA = tanh_f(ga[2] + biasS[up * 8 + 2]);
      float oA = sigm(ga[3] + biasS[up * 8 + 3]);
      cA = fA * cA + iA * gA;
      float hA = oA * tanh_f(cA);
      float iB = sigm(gv[0] + biasS[up * 8 + 4]);
      float fB = sigm(gv[1] + biasS[up * 8 + 5]);
      float gB = tanh_f(gv[2] + biasS[up * 8 + 6]);
      float oB = sigm(gv[3] + biasS[up * 8 + 7]);
      cB = fB * cB + iB * gB;
      float hB = oB * tanh_f(cB);
      unsigned hv = (unsigned)f2bf(hA) | ((unsigned)f2bf(hB) << 16);
      unsigned* dst = (unsigned*)(LAYER ? h2bc : h1bc);
      size_t di = ((size_t)(t & (RING - 1)) * B_TOT * HP + (size_t)(b0 + eb) * HP + u0) >> 1;
      __hip_atomic_store(dst + di + up, hv, __ATOMIC_RELAXED, __HIP_MEMORY_SCOPE_AGENT);
    }

    // barrier drains every wave's vmcnt(0) -> all sc1 h stores are LIC-visible;
    // then a RELAXED sc1 flag store suffices (no release/wbl2 needed: nothing
    // cross-wg-visible sits dirty in L2).
    __syncthreads();
    if (tid == 0)
      __hip_atomic_store(mys, t + 1, __ATOMIC_RELAXED, __HIP_MEMORY_SCOPE_AGENT);

    // ---- head: y[b, t-1] from staged h2[t-1] — AFTER signal (off crit path)
    if (LAYER == 1 && gg == 0 && t > 0) {
      int eb = tid >> 3, uc = tid & 7;
      float sum = 0.f;
#pragma unroll
      for (int j = 0; j < 4; ++j) {
        short8 hvv = *(const short8*)&inA[eb][HP + uc * 32 + j * 8];
#pragma unroll
        for (int e = 0; e < 8; ++e)
          sum += bf2f((unsigned short)hvv[e]) * wlinS[uc * 32 + j * 8 + e];
      }
      sum += __shfl_xor(sum, 1);
      sum += __shfl_xor(sum, 2);
      sum += __shfl_xor(sum, 4);
      if ((tid & 7) == 0)
        out[(size_t)(b0 + eb) * T_LEN + (t - 1)] = sigm(sum + blinv);
    }
  }

  // ---- epilogue: y[:, 511] after all layer1 wgs finished t=511 ----
  if (LAYER == 1 && gg == 0) {
    if (wv == 0 && lane < 16) {
      const int* sl = c1s + lane * SLOTS;
      while (__hip_atomic_load(sl, __ATOMIC_RELAXED, __HIP_MEMORY_SCOPE_AGENT) < T_LEN) {
        __builtin_amdgcn_s_sleep(1);
      }
    }
    __syncthreads();
    int eb = tid >> 3, uc = tid & 7;
    const unsigned* src =
        (const unsigned*)(h2bc + (size_t)(511 & (RING - 1)) * B_TOT * HP +
                          (size_t)(b0 + eb) * HP + uc * 32);
    float sum = 0.f;
#pragma unroll
    for (int j = 0; j < 16; ++j) {
      unsigned dw = ld_lic(src + j);
      sum += bf2f((unsigned short)(dw & 0xFFFFu)) * wlinS[uc * 32 + j * 2];
      sum += bf2f((unsigned short)(dw >> 16)) * wlinS[uc * 32 + j * 2 + 1];
    }
    sum += __shfl_xor(sum, 1);
    sum += __shfl_xor(sum, 2);
    sum += __shfl_xor(sum, 4);
    if ((tid & 7) == 0)
      out[(size_t)(b0 + eb) * T_LEN + 511] = sigm(sum + blinv);
  }
}

// ---------------------------------------------------------------------------
extern "C" __global__ void __launch_bounds__(256, 1) lstm_persist(
    const float* __restrict__ x,
    const float* __restrict__ Wih0, const float* __restrict__ Whh0,
    const float* __restrict__ bih0, const float* __restrict__ bhh0,
    const float* __restrict__ Wih1, const float* __restrict__ Whh1,
    const float* __restrict__ bih1, const float* __restrict__ bhh1,
    const float* __restrict__ Wlin, const float* __restrict__ blin,
    float* __restrict__ out,
    unsigned short* __restrict__ h1bc, unsigned short* __restrict__ h2bc,
    int* __restrict__ cnt) {
  __shared__ unsigned short WL[NR][LDSK];    // 66560 B  bf16 [r][k], r = lu*4+gate
  __shared__ unsigned short inA[MB][LDSK];   // 33280 B  bf16 [b][k]
  __shared__ float gbuf[MB][NR + 4];         //  8704 B  fp32 gate preacts
  __shared__ float biasS[NR];
  __shared__ float wlinS[HP];

  const int tid = threadIdx.x;
  const int wg = blockIdx.x;
  const int layer = wg >> 7;
  const int gb = (wg >> 4) & 7;
  const int gg = wg & 15;
  const int b0 = gb * MB, u0 = gg * NU;

  // ---- one-time LDS fills ----
  {
    const float* Wih = layer ? Wih1 : Wih0;
    const float* Whh = layer ? Whh1 : Whh0;
    const float* bi = layer ? bih1 : bih0;
    const float* bh = layer ? bhh1 : bhh0;
    const int K = layer ? K1 : K0;
    const int xw = layer ? NH : NX;     // real width of input-part
    const int xofs = layer ? HP : XP;   // where h-part starts
    int r = tid >> 2, c = tid & 3;
    int lu = r >> 2, g = r & 3, ug = u0 + lu;
    int row = g * NH + ug;
    int kq = K >> 2;
    for (int k = c * kq; k < (c + 1) * kq; ++k) {
      float v = 0.f;
      if (ug < NH) {
        if (k < xw) v = Wih[(size_t)row * xw + k];
        else if (k >= xofs && k < xofs + NH) v = Whh[(size_t)row * NH + (k - xofs)];
      }
      WL[r][k] = f2bf(v);
    }
    if (tid < NR) {
      int lu2 = tid >> 2, g2 = tid & 3, ug2 = u0 + lu2;
      biasS[tid] = (ug2 < NH) ? (bi[g2 * NH + ug2] + bh[g2 * NH + ug2]) : 0.f;
    }
    if (tid < HP) wlinS[tid] = (tid < NH) ? Wlin[tid] : 0.f;
    for (int i = tid; i < MB * LDSK; i += 256) ((unsigned short*)inA)[i] = 0;
  }
  __syncthreads();

  float blinv = blin[0];
  int* c0s = cnt + gb * 16 * SLOTS;              // layer0 slots, batch-group gb
  int* c1s = cnt + (8 + gb) * 16 * SLOTS;        // layer1 slots
  int* mys = (layer ? c1s : c0s) + gg * SLOTS;   // own slot

  if (layer == 0)
    run_layer<K0 / 32, 0>(tid, gg, b0, u0, x, out, blinv, h1bc, h2bc,
                          c0s, c1s, mys, WL, inA, gbuf, biasS, wlinS);
  else
    run_layer<K1 / 32, 1>(tid, gg, b0, u0, x, out, blinv, h1bc, h2bc,
                          c0s, c1s, mys, WL, inA, gbuf, biasS, wlinS);
}

extern "C" __global__ void prep_zero(int* cnt) {
  int i = blockIdx.x * 256 + threadIdx.x;
  if (i < 2 * 8 * 16 * SLOTS)
    __hip_atomic_store(cnt + i, 0, __ATOMIC_RELAXED, __HIP_MEMORY_SCOPE_AGENT);
}

// ---------------------------------------------------------------------------
extern "C" void kernel_launch(void* const* d_in, const int* in_sizes, int n_in,
                              void* d_out, int out_size, void* d_ws, size_t ws_size,
                              hipStream_t stream) {
  const float* x    = (const float*)d_in[0];
  const float* Wih0 = (const float*)d_in[1];
  const float* Whh0 = (const float*)d_in[2];
  const float* bih0 = (const float*)d_in[3];
  const float* bhh0 = (const float*)d_in[4];
  const float* Wih1 = (const float*)d_in[5];
  const float* Whh1 = (const float*)d_in[6];
  const float* bih1 = (const float*)d_in[7];
  const float* bhh1 = (const float*)d_in[8];
  const float* Wlin = (const float*)d_in[9];
  const float* blin = (const float*)d_in[10];
  float* out = (float*)d_out;

  // workspace carve: h1bc 2MB | h2bc 2MB | slot counters 16KB
  unsigned short* h1bc = (unsigned short*)d_ws;
  unsigned short* h2bc = h1bc + (size_t)RING * B_TOT * HP;
  int* cnt = (int*)((char*)d_ws + 2u * (size_t)RING * B_TOT * HP * sizeof(unsigned short));

  hipLaunchKernelGGL(prep_zero, dim3(16), dim3(256), 0, stream, cnt);

  void* args[] = {&x, &Wih0, &Whh0, &bih0, &bhh0, &Wih1, &Whh1, &bih1, &bhh1,
                  &Wlin, &blin, &out, &h1bc, &h2bc, &cnt};
  hipLaunchCooperativeKernel((void*)lstm_persist, dim3(256), dim3(256), args, 0u, stream);
}